// Round 16
// baseline (102.380 us; speedup 1.0000x reference)
//
#include <hip/hip_runtime.h>

// SAGEConv (mean aggr, root weight, L2 normalize), fp32 in/out.
// R16: (a) gm gather 4 nodes/wave in ONE round (32 gathers in flight);
//      (b) cursor padded to 1 counter per 64B line (kills same-line atomic
//      serialization in fill). Structure otherwise = R15.

typedef __attribute__((ext_vector_type(8))) short short8;   // 8 bf16 = 4 VGPRs
typedef __attribute__((ext_vector_type(4))) float floatx4;  // MFMA acc

constexpr int kNodes = 50000;
constexpr int kEdges = 800000;
constexpr int kF = 96;          // input features
constexpr int kH = 128;         // output features
constexpr int kEllW = 32;       // ELL width (Poisson(16): P(deg>32) ~ 1e-5)
constexpr int kSpillCap = 4096;
constexpr int kBktRange = kNodes / 8;  // 6250 nodes per XCD-group
constexpr int kCurStride = 16;  // cursor stride in ints: 1 counter per 64B line

// workspace byte offsets
constexpr size_t kXhOff    = 0;                               // 9,600,000
constexpr size_t kWhOff    = 19200000;                        // 49,152
constexpr size_t kEllOff   = 19249152;                        // 3,200,000 (ushort)
constexpr size_t kCurOff   = 22449152;                        // 3,200,000 (padded cursor)
constexpr size_t kSpcOff   = 25649152;                        // 4 (spillCnt)
constexpr size_t kSpillOff = 25649168;                        // 16,384

// mega kernel: period-11 interleave, 782 periods
constexpr int kPeriods    = 782;
constexpr int kMegaBlocks = kPeriods * 11;        // 8602
constexpr int kPrepBlocks = kPeriods * 3;         // 2346
constexpr int kPrepItems  = kNodes * kF / 8 + kH * 192 / 8;   // 603072
constexpr int kPrepStride = kPrepBlocks * 256;    // 600576

constexpr int kRowS = 104;   // LDS row stride in shorts (208 B): 2-way-only conflicts

__device__ __forceinline__ unsigned pack2_bf16(float a, float b) {
  unsigned ua = __float_as_uint(a), ub = __float_as_uint(b);
  ua = (ua + 0x7fffu + ((ua >> 16) & 1u)) >> 16;   // RNE
  ub = (ub + 0x7fffu + ((ub >> 16) & 1u)) >> 16;
  return ua | (ub << 16);
}
__device__ __forceinline__ float bf_lo(unsigned u) { return __uint_as_float(u << 16); }
__device__ __forceinline__ float bf_hi(unsigned u) { return __uint_as_float(u & 0xffff0000u); }

// ELL row layout is slot-transposed: entry j lives at (j&3)*8 + (j>>2), so
// slot s's 8 entries (j = 4k+s) are the contiguous ushorts [s*8, s*8+8).
__device__ __forceinline__ void ell_insert(int dst, int src, int* cursor,
                                           ushort* ell, unsigned* spill,
                                           int* spillCnt) {
  const int slot = atomicAdd(&cursor[(size_t)dst * kCurStride], 1);
  if (slot < kEllW) {
    ell[(size_t)dst * kEllW + ((slot & 3) << 3) + (slot >> 2)] = (ushort)src;
  } else {
    const int sp = atomicAdd(spillCnt, 1);
    if (sp < kSpillCap) spill[sp] = ((unsigned)dst << 16) | (unsigned)src;
  }
}

// --- mega: period-11 interleave; fill group = blockIdx&7 (XCD-aligned) -------
__global__ void __launch_bounds__(256)
mega_kernel(const int* __restrict__ ei, const float* __restrict__ x,
            const float* __restrict__ Wl, const float* __restrict__ Wr,
            uint4* __restrict__ xh4, uint4* __restrict__ wh4,
            int* __restrict__ cursor, ushort* __restrict__ ell,
            unsigned* __restrict__ spill, int* __restrict__ spillCnt) {
  const int p = blockIdx.x / 11;
  const int r = blockIdx.x % 11;
  if (r < 8) {
    // group g = blockIdx&7 matches the XCD round-robin; for fixed p the 8
    // fill blocks' (3p+r)&7 values cover {0..7} bijectively -> exact coverage.
    const int g = blockIdx.x & 7;
    const int lo = g * kBktRange, hi = lo + kBktRange;
    const int base = p * 1024 + threadIdx.x;
    int d[4];
#pragma unroll
    for (int k = 0; k < 4; ++k) {
      const int e = base + k * 256;
      d[k] = (e < kEdges) ? ei[kEdges + e] : -1;
    }
#pragma unroll
    for (int k = 0; k < 4; ++k) {
      if (d[k] >= lo && d[k] < hi) {
        const int e = base + k * 256;
        ell_insert(d[k], ei[e], cursor, ell, spill, spillCnt);
      }
    }
    return;
  }
  constexpr int kCvt = kNodes * kF / 8;     // 600000
  const int pid = p * 3 + (r - 8);          // 0..2345
  for (int i = pid * 256 + threadIdx.x; i < kPrepItems; i += kPrepStride) {
    if (i < kCvt) {
      const float4 v0 = reinterpret_cast<const float4*>(x)[i * 2];
      const float4 v1 = reinterpret_cast<const float4*>(x)[i * 2 + 1];
      uint4 o;
      o.x = pack2_bf16(v0.x, v0.y);
      o.y = pack2_bf16(v0.z, v0.w);
      o.z = pack2_bf16(v1.x, v1.y);
      o.w = pack2_bf16(v1.z, v1.w);
      xh4[i] = o;
    } else {
      const int j = i - kCvt;
      const int row = j / 24, chunk = j % 24;
      const float* src = (chunk < 12) ? (Wl + (size_t)row * kF + chunk * 8)
                                      : (Wr + (size_t)row * kF + (chunk - 12) * 8);
      const float4 v0 = reinterpret_cast<const float4*>(src)[0];
      const float4 v1 = reinterpret_cast<const float4*>(src)[1];
      uint4 o;
      o.x = pack2_bf16(v0.x, v0.y);
      o.y = pack2_bf16(v0.z, v0.w);
      o.z = pack2_bf16(v1.x, v1.y);
      o.w = pack2_bf16(v1.z, v1.w);
      wh4[j] = o;
    }
  }
}

// --- fused gather + MFMA, 4 waves per 16-node tile ---------------------------
// Wave w gathers its 4 nodes in ONE round: 4 vector index loads + 32
// independent predicated gathers in flight. Then MFMA (wave w owns channel
// groups {2w,2w+1}); ssq cross-wave reduced via LDS.
__global__ void __launch_bounds__(256)
gm_kernel(const uint4* __restrict__ xh4, const int* __restrict__ cursor,
          const ushort* __restrict__ ell, const unsigned* __restrict__ spill,
          const int* __restrict__ spillCnt, const uint4* __restrict__ wh4,
          const float* __restrict__ bl, float* __restrict__ out) {
  __shared__ __align__(16) short sAgg[16 * kRowS];   // 16 rows x 208 B
  __shared__ float sP[4][4][4];                      // [wave][q][reg]

  const int wave = threadIdx.x >> 6, lane = threadIdx.x & 63;
  // XCD-bucket-aligned tile map: group g gets tiles [g*3125/8, (g+1)*3125/8)
  const int g = blockIdx.x & 7;
  const int j = blockIdx.x >> 3;
  const int tstart = (g * 3125) >> 3;
  const int tend = ((g + 1) * 3125) >> 3;
  const int tile = tstart + j;
  if (tile >= tend) return;
  const int base = tile * 16;

  // ---- phase A: gather 4 nodes in one round ----
  const int slot = lane / 12;
  const int c = lane % 12;
  const bool gactive = lane < 48;
  const int slotc = gactive ? slot : 0;      // keep inactive lanes in-row
  const int sc = min(*spillCnt, kSpillCap);  // ~always 0
  const int n0 = base + wave * 4;

  int deg[4], dm[4];
  uint4 iv[4];
#pragma unroll
  for (int n = 0; n < 4; ++n) {
    deg[n] = cursor[(size_t)(n0 + n) * kCurStride];
    iv[n] = *reinterpret_cast<const uint4*>(
        ell + (size_t)(n0 + n) * kEllW + (slotc << 3));
  }
#pragma unroll
  for (int n = 0; n < 4; ++n) dm[n] = min(deg[n], kEllW);

  float acc[4][8];
#pragma unroll
  for (int n = 0; n < 4; ++n)
#pragma unroll
    for (int k = 0; k < 8; ++k) acc[n][k] = 0.f;

#pragma unroll
  for (int k = 0; k < 8; ++k) {
    const int idx = (k << 2) + slot;   // original ELL position
#pragma unroll
    for (int n = 0; n < 4; ++n) {
      const unsigned wrd = (k < 2) ? iv[n].x
                         : (k < 4) ? iv[n].y
                         : (k < 6) ? iv[n].z : iv[n].w;
      const int src = (k & 1) ? (int)(wrd >> 16) : (int)(wrd & 0xffffu);
      if (gactive && idx < dm[n]) {
        const uint4 v = xh4[(size_t)src * 12 + c];
        acc[n][0] += bf_lo(v.x); acc[n][1] += bf_hi(v.x);
        acc[n][2] += bf_lo(v.y); acc[n][3] += bf_hi(v.y);
        acc[n][4] += bf_lo(v.z); acc[n][5] += bf_hi(v.z);
        acc[n][6] += bf_lo(v.w); acc[n][7] += bf_hi(v.w);
      }
    }
  }
  // spill edges (rare)
  for (int jj = 0; jj < sc; ++jj) {
    const unsigned pr = spill[jj];
    const int rel = (int)(pr >> 16) - n0;
    if (lane < 12 && rel >= 0 && rel < 4) {
      const uint4 v = xh4[(size_t)(pr & 0xffffu) * 12 + c];
#pragma unroll
      for (int n = 0; n < 4; ++n) {
        if (rel == n) {
          acc[n][0] += bf_lo(v.x); acc[n][1] += bf_hi(v.x);
          acc[n][2] += bf_lo(v.y); acc[n][3] += bf_hi(v.y);
          acc[n][4] += bf_lo(v.z); acc[n][5] += bf_hi(v.z);
          acc[n][6] += bf_lo(v.w); acc[n][7] += bf_hi(v.w);
        }
      }
    }
  }
  // combine 4 slots -> lanes 0..11 (per node, 2 shfl rounds)
#pragma unroll
  for (int n = 0; n < 4; ++n) {
#pragma unroll
    for (int k = 0; k < 8; ++k) {
      acc[n][k] += __shfl(acc[n][k], lane + 24, 64);
      acc[n][k] += __shfl(acc[n][k], lane + 12, 64);
    }
  }
  if (lane < 12) {
#pragma unroll
    for (int n = 0; n < 4; ++n) {
      const float inv = 1.0f / fmaxf((float)deg[n], 1.0f);
      uint4 o;
      o.x = pack2_bf16(acc[n][0] * inv, acc[n][1] * inv);
      o.y = pack2_bf16(acc[n][2] * inv, acc[n][3] * inv);
      o.z = pack2_bf16(acc[n][4] * inv, acc[n][5] * inv);
      o.w = pack2_bf16(acc[n][6] * inv, acc[n][7] * inv);
      *reinterpret_cast<uint4*>(&sAgg[(wave * 4 + n) * kRowS + c * 8]) = o;
    }
  }
  __syncthreads();

  // ---- phase B: MFMA, wave w owns channel-groups {2w, 2w+1} ----
  const int r = lane & 15, q = lane >> 4;
  const int cg0 = wave * 2;
  const short8* xhS = reinterpret_cast<const short8*>(xh4);
  const short8* whS = reinterpret_cast<const short8*>(wh4);

  floatx4 fac[2] = {};
#pragma unroll
  for (int ks = 0; ks < 6; ++ks) {
    short8 a;
    if (ks < 3) {
      a = *reinterpret_cast<const short8*>(&sAgg[r * kRowS + (ks * 4 + q) * 8]);
    } else {
      a = xhS[(size_t)(base + r) * 12 + (ks - 3) * 4 + q];
    }
#pragma unroll
    for (int i = 0; i < 2; ++i) {
      const short8 b = whS[((cg0 + i) * 16 + r) * 24 + ks * 4 + q];
      fac[i] = __builtin_amdgcn_mfma_f32_16x16x32_bf16(a, b, fac[i], 0, 0, 0);
    }
  }

  float p0 = 0.f, p1 = 0.f, p2 = 0.f, p3 = 0.f;
#pragma unroll
  for (int i = 0; i < 2; ++i) {
    const float bb = bl[(cg0 + i) * 16 + r];
    fac[i][0] += bb; fac[i][1] += bb; fac[i][2] += bb; fac[i][3] += bb;
    p0 += fac[i][0] * fac[i][0];
    p1 += fac[i][1] * fac[i][1];
    p2 += fac[i][2] * fac[i][2];
    p3 += fac[i][3] * fac[i][3];
  }
#pragma unroll
  for (int off = 1; off < 16; off <<= 1) {
    p0 += __shfl_xor(p0, off, 64);
    p1 += __shfl_xor(p1, off, 64);
    p2 += __shfl_xor(p2, off, 64);
    p3 += __shfl_xor(p3, off, 64);
  }
  if (r == 0) {
    sP[wave][q][0] = p0; sP[wave][q][1] = p1;
    sP[wave][q][2] = p2; sP[wave][q][3] = p3;
  }
  __syncthreads();
  const float t0 = sP[0][q][0] + sP[1][q][0] + sP[2][q][0] + sP[3][q][0];
  const float t1 = sP[0][q][1] + sP[1][q][1] + sP[2][q][1] + sP[3][q][1];
  const float t2 = sP[0][q][2] + sP[1][q][2] + sP[2][q][2] + sP[3][q][2];
  const float t3 = sP[0][q][3] + sP[1][q][3] + sP[2][q][3] + sP[3][q][3];
  const float s0 = 1.0f / fmaxf(sqrtf(t0), 1e-12f);
  const float s1 = 1.0f / fmaxf(sqrtf(t1), 1e-12f);
  const float s2 = 1.0f / fmaxf(sqrtf(t2), 1e-12f);
  const float s3 = 1.0f / fmaxf(sqrtf(t3), 1e-12f);

#pragma unroll
  for (int i = 0; i < 2; ++i) {
    const int col = (cg0 + i) * 16 + r;
    float* o = out + (size_t)(base + q * 4) * kH + col;
    o[0 * kH] = fac[i][0] * s0;
    o[1 * kH] = fac[i][1] * s1;
    o[2 * kH] = fac[i][2] * s2;
    o[3 * kH] = fac[i][3] * s3;
  }
}

extern "C" void kernel_launch(void* const* d_in, const int* in_sizes, int n_in,
                              void* d_out, int out_size, void* d_ws, size_t ws_size,
                              hipStream_t stream) {
  const int*   ei = (const int*)d_in[0];
  const float* x  = (const float*)d_in[1];
  const float* Wl = (const float*)d_in[2];
  const float* bl = (const float*)d_in[3];
  const float* Wr = (const float*)d_in[4];
  float* out = (float*)d_out;

  char* ws = (char*)d_ws;
  uint4*    xh4      = (uint4*)(ws + kXhOff);
  uint4*    wh4      = (uint4*)(ws + kWhOff);
  ushort*   ell      = (ushort*)(ws + kEllOff);
  int*      cursor   = (int*)(ws + kCurOff);
  int*      spillCnt = (int*)(ws + kSpcOff);
  unsigned* spill    = (unsigned*)(ws + kSpillOff);

  // zero padded cursor (3.2 MB) + spillCnt (adjacent)
  hipMemsetAsync(ws + kCurOff, 0, 3200008, stream);

  mega_kernel<<<kMegaBlocks, 256, 0, stream>>>(ei, x, Wl, Wr, xh4, wh4, cursor,
                                               ell, spill, spillCnt);

  // 391 tile-slots x 8 XCD groups (3125 tiles, bucket-aligned)
  gm_kernel<<<391 * 8, 256, 0, stream>>>(xh4, cursor, ell, spill, spillCnt,
                                         wh4, bl, out);
}